// Round 7
// baseline (528.464 us; speedup 1.0000x reference)
//
#include <hip/hip_runtime.h>

#define NWIN 2048
#define NPOS 64
#define DIM  192
#define C3   576
#define HEADS 6
#define HD   32
#define MTOT (NWIN*NPOS)
#define SCALE 0.17677669529663687f

typedef __bf16 b16x8 __attribute__((ext_vector_type(8)));
typedef __bf16 b16x4 __attribute__((ext_vector_type(4)));
typedef float  f32x4 __attribute__((ext_vector_type(4)));

// load 8 contiguous elements as bf16x8, converting if fp32
__device__ __forceinline__ b16x8 ld8(const float* p) {
    const f32x4 f0 = *(const f32x4*)p;
    const f32x4 f1 = *(const f32x4*)(p + 4);
    b16x8 r;
    r[0] = (__bf16)f0[0]; r[1] = (__bf16)f0[1]; r[2] = (__bf16)f0[2]; r[3] = (__bf16)f0[3];
    r[4] = (__bf16)f1[0]; r[5] = (__bf16)f1[1]; r[6] = (__bf16)f1[2]; r[7] = (__bf16)f1[3];
    return r;
}
__device__ __forceinline__ b16x8 ld8(const __bf16* p) { return *(const b16x8*)p; }

// ---------------------------------------------------------------------------
// GEMM (B^T form): C[m][n] = sum_k A[m][k] * W[n][k] + bias[n]
// Tile 128(M) x GTNT(N), BK=64 (3 chunks), 256 threads = 4 waves.
// GTNT=192: A panel re-read N/192 times (3x for C3, 1x for DIM) instead of 9x.
// LDS = (128+192)*72*2 = 45 KB; 3 blocks/CU = 135 KB <= 160 KB.
// XCD-chunk swizzle: every grid used here is a multiple of 8.
// ---------------------------------------------------------------------------
#define GTM 128
#define GLD 72

template <typename TA, typename TW, typename TC, int GTNT>
__global__ __launch_bounds__(256, 3)
void gemm_bt(const TA* __restrict__ A, const TW* __restrict__ W,
             const float* __restrict__ bias, TC* __restrict__ C, int N)
{
    constexpr int NT = GTNT / 16;
    __shared__ __bf16 As[GTM][GLD];
    __shared__ __bf16 Ws[GTNT][GLD];
    const int ntiles = N / GTNT;
    const int cpx = gridDim.x >> 3;                       // grid % 8 == 0
    const int lb  = (blockIdx.x & 7) * cpx + (blockIdx.x >> 3);
    const int bm = lb / ntiles;
    const int bn = lb % ntiles;
    const long m0 = (long)bm * GTM;
    const int  n0 = bn * GTNT;
    const int tid  = threadIdx.x;
    const int wave = tid >> 6, lane = tid & 63;
    const int lr = lane & 15, lq = lane >> 4;

    f32x4 acc[2][NT];
#pragma unroll
    for (int i = 0; i < 2; i++)
#pragma unroll
        for (int j = 0; j < NT; j++) acc[i][j] = (f32x4){0.f, 0.f, 0.f, 0.f};

    for (int kc = 0; kc < 3; kc++) {
#pragma unroll
        for (int i = 0; i < 4; i++) {
            int idx = tid + i * 256;
            int r = idx >> 3, c = idx & 7;
            *(b16x8*)&As[r][c * 8] = ld8(A + (m0 + r) * 192 + kc * 64 + c * 8);
        }
#pragma unroll
        for (int i = 0; i < GTNT / 32; i++) {
            int idx = tid + i * 256;
            int r = idx >> 3, c = idx & 7;
            *(b16x8*)&Ws[r][c * 8] = ld8(W + (long)(n0 + r) * 192 + kc * 64 + c * 8);
        }
        __syncthreads();
#pragma unroll
        for (int kt = 0; kt < 2; kt++) {
            const int k0 = kt * 32 + lq * 8;
            b16x8 a0 = *(const b16x8*)&As[wave * 32 + lr][k0];
            b16x8 a1 = *(const b16x8*)&As[wave * 32 + 16 + lr][k0];
#pragma unroll
            for (int tn = 0; tn < NT; tn++) {
                b16x8 bb = *(const b16x8*)&Ws[tn * 16 + lr][k0];
                acc[0][tn] = __builtin_amdgcn_mfma_f32_16x16x32_bf16(a0, bb, acc[0][tn], 0, 0, 0);
                acc[1][tn] = __builtin_amdgcn_mfma_f32_16x16x32_bf16(a1, bb, acc[1][tn], 0, 0, 0);
            }
        }
        __syncthreads();
    }
#pragma unroll
    for (int tn = 0; tn < NT; tn++) {
        float bv = bias[n0 + tn * 16 + lr];
#pragma unroll
        for (int tm = 0; tm < 2; tm++) {
#pragma unroll
            for (int r = 0; r < 4; r++) {
                long row = m0 + wave * 32 + tm * 16 + lq * 4 + r;
                C[row * N + (n0 + tn * 16 + lr)] = (TC)(acc[tm][tn][r] + bv);
            }
        }
    }
}

// ---------------------------------------------------------------------------
// Depthwise 3x3 conv, rolling-window v3.
// Block = 384 threads = (mr 0..7) x (cg 0..47): one (window b, channel-third).
// vs v2: 8 rows/thread (was 16) -> 2x wave parallelism; FULL unroll of the
// rolling loop -> compiler pipelines all ~27 loads instead of a 4-iter window.
// Both target the latency-bound signature (Occ 33%, VALU 29%, HBM 22%).
// grid = 2048*3 = 6144, XCD-chunk swizzled (halo rows b-1/b+1 are L2/L3 hits).
// SCALE for q channels folded into weights+bias.
// ---------------------------------------------------------------------------
__device__ __forceinline__ void ld4f(float* d, const __bf16* p) {
    b16x4 v = *(const b16x4*)p;
    d[0] = (float)v[0]; d[1] = (float)v[1]; d[2] = (float)v[2]; d[3] = (float)v[3];
}

__global__ __launch_bounds__(384)
void dwconv(const __bf16* __restrict__ t, const float* __restrict__ dw_w,
            const float* __restrict__ dw_b, __bf16* __restrict__ u)
{
    const int tid = threadIdx.x;
    const int cg  = tid % 48;
    const int mr  = tid / 48;                       // 0..7
    const int cpx = gridDim.x >> 3;
    const int lb  = (blockIdx.x & 7) * cpx + (blockIdx.x >> 3);
    const int b   = lb / 3;
    const int gq  = lb % 3;
    const int ch0 = gq * 192 + cg * 4;

    const float sc = (ch0 < DIM) ? SCALE : 1.0f;
    float w[9][4], bs[4];
#pragma unroll
    for (int e = 0; e < 4; e++) {
        bs[e] = dw_b[ch0 + e] * sc;
#pragma unroll
        for (int tp = 0; tp < 9; tp++) w[tp][e] = dw_w[(ch0 + e) * 9 + tp] * sc;
    }

    const bool up = (b > 0), dn = (b < NWIN - 1);
    const __bf16* r0 = t + ((long)(b - 1) * NPOS) * C3 + ch0;
    const __bf16* r1 = t + ((long)b       * NPOS) * C3 + ch0;
    const __bf16* r2 = t + ((long)(b + 1) * NPOS) * C3 + ch0;
    const int n0 = mr * 8;
    __bf16* ub = u + ((long)b * NPOS + n0) * C3 + ch0;

    // rolling registers: p* = col n-1, c* = col n (rows b-1, b, b+1)
    float p0[4] = {0,0,0,0}, p1[4] = {0,0,0,0}, p2[4] = {0,0,0,0};
    float c0[4] = {0,0,0,0}, c1[4] = {0,0,0,0}, c2[4] = {0,0,0,0};
    if (n0 > 0) {
        const long off = (long)(n0 - 1) * C3;
        if (up) ld4f(p0, r0 + off);
        ld4f(p1, r1 + off);
        if (dn) ld4f(p2, r2 + off);
    }
    {
        const long off = (long)n0 * C3;
        if (up) ld4f(c0, r0 + off);
        ld4f(c1, r1 + off);
        if (dn) ld4f(c2, r2 + off);
    }

#pragma unroll
    for (int j = 0; j < 8; j++) {
        const int n = n0 + j;
        float x0[4] = {0,0,0,0}, x1[4] = {0,0,0,0}, x2[4] = {0,0,0,0};
        if (n < 63) {
            const long off = (long)(n + 1) * C3;
            if (up) ld4f(x0, r0 + off);
            ld4f(x1, r1 + off);
            if (dn) ld4f(x2, r2 + off);
        }
        b16x4 o;
#pragma unroll
        for (int e = 0; e < 4; e++) {
            float a = bs[e]
                + w[0][e] * p0[e] + w[1][e] * c0[e] + w[2][e] * x0[e]
                + w[3][e] * p1[e] + w[4][e] * c1[e] + w[5][e] * x1[e]
                + w[6][e] * p2[e] + w[7][e] * c2[e] + w[8][e] * x2[e];
            o[e] = (__bf16)a;
        }
        *(b16x4*)(ub + (long)j * C3) = o;
#pragma unroll
        for (int e = 0; e < 4; e++) {
            p0[e] = c0[e]; c0[e] = x0[e];
            p1[e] = c1[e]; c1[e] = x1[e];
            p2[e] = c2[e]; c2[e] = x2[e];
        }
    }
}

// ---------------------------------------------------------------------------
// MFMA window attention on pre-conv'd qkv (u). One wave per (b, h). Unchanged.
// ---------------------------------------------------------------------------
#define P0v2 0
#define VT0  4608

__global__ __launch_bounds__(64, 3)
void attn_mfma(const __bf16* __restrict__ u, const float* __restrict__ mask,
               const float* __restrict__ rpb, __bf16* __restrict__ ctx)
{
    __shared__ __bf16 smem[4608 + 2304];
    __shared__ float  rpb_h[225];
    const int cpx = gridDim.x >> 3;
    const int lb  = (blockIdx.x & 7) * cpx + (blockIdx.x >> 3);
    const int b = lb / HEADS;
    const int h = lb % HEADS;
    const int lane = threadIdx.x;
    const int lr = lane & 15, lq = lane >> 4;

    for (int i = lane; i < 225; i += 64) rpb_h[i] = rpb[i * HEADS + h];

    const __bf16* ub = u + (long)b * NPOS * C3 + h * HD;

    {
        const __bf16* vp = ub + (long)lane * C3 + 2 * DIM;
        b16x8 v0 = *(const b16x8*)vp;
        b16x8 v1 = *(const b16x8*)(vp + 8);
        b16x8 v2 = *(const b16x8*)(vp + 16);
        b16x8 v3 = *(const b16x8*)(vp + 24);
#pragma unroll
        for (int e = 0; e < 8; e++) {
            smem[VT0 + (e     ) * 72 + lane] = v0[e];
            smem[VT0 + (e +  8) * 72 + lane] = v1[e];
            smem[VT0 + (e + 16) * 72 + lane] = v2[e];
            smem[VT0 + (e + 24) * 72 + lane] = v3[e];
        }
    }

    b16x8 aq[4], bk[4];
#pragma unroll
    for (int t4 = 0; t4 < 4; t4++) {
        aq[t4] = *(const b16x8*)(ub + (long)(t4 * 16 + lr) * C3 +       lq * 8);
        bk[t4] = *(const b16x8*)(ub + (long)(t4 * 16 + lr) * C3 + DIM + lq * 8);
    }

    f32x4 S[4][4];
#pragma unroll
    for (int tm = 0; tm < 4; tm++)
#pragma unroll
        for (int tn = 0; tn < 4; tn++) {
            S[tm][tn] = (f32x4){0.f, 0.f, 0.f, 0.f};
            S[tm][tn] = __builtin_amdgcn_mfma_f32_16x16x32_bf16(aq[tm], bk[tn], S[tm][tn], 0, 0, 0);
        }

    __syncthreads();

    const float* mbase = mask + (long)(b & 63) * 4096;
    float part[4][4];
#pragma unroll
    for (int tm = 0; tm < 4; tm++)
#pragma unroll
        for (int r = 0; r < 4; r++) part[tm][r] = 0.f;
#pragma unroll
    for (int tm = 0; tm < 4; tm++) {
#pragma unroll
        for (int r = 0; r < 4; r++) {
            const int row = tm * 16 + lq * 4 + r;
            const int rh = row >> 3, rw = row & 7;
#pragma unroll
            for (int tn = 0; tn < 4; tn++) {
                const int col = tn * 16 + lr;
                const int ridx = (rh - (col >> 3) + 7) * 15 + (rw - (col & 7) + 7);
                float sv = S[tm][tn][r] + rpb_h[ridx] + mbase[row * 64 + col];
                float ee = __expf(sv);
                part[tm][r] += ee;
                smem[P0v2 + row * 72 + col] = (__bf16)ee;
            }
        }
    }
#pragma unroll
    for (int st = 1; st < 16; st <<= 1)
#pragma unroll
        for (int tm = 0; tm < 4; tm++)
#pragma unroll
            for (int r = 0; r < 4; r++) part[tm][r] += __shfl_xor(part[tm][r], st);
    float inv[4][4];
#pragma unroll
    for (int tm = 0; tm < 4; tm++)
#pragma unroll
        for (int r = 0; r < 4; r++) inv[tm][r] = 1.0f / part[tm][r];

    __syncthreads();

    f32x4 O[4][2];
#pragma unroll
    for (int tm = 0; tm < 4; tm++)
#pragma unroll
        for (int tn2 = 0; tn2 < 2; tn2++) O[tm][tn2] = (f32x4){0.f, 0.f, 0.f, 0.f};
#pragma unroll
    for (int tk = 0; tk < 2; tk++) {
        b16x8 bv[2];
#pragma unroll
        for (int tn2 = 0; tn2 < 2; tn2++)
            bv[tn2] = *(const b16x8*)&smem[VT0 + (tn2 * 16 + lr) * 72 + tk * 32 + lq * 8];
#pragma unroll
        for (int tm = 0; tm < 4; tm++) {
            b16x8 ap = *(const b16x8*)&smem[P0v2 + (tm * 16 + lr) * 72 + tk * 32 + lq * 8];
#pragma unroll
            for (int tn2 = 0; tn2 < 2; tn2++)
                O[tm][tn2] = __builtin_amdgcn_mfma_f32_16x16x32_bf16(ap, bv[tn2], O[tm][tn2], 0, 0, 0);
        }
    }

#pragma unroll
    for (int tm = 0; tm < 4; tm++)
#pragma unroll
        for (int tn2 = 0; tn2 < 2; tn2++)
#pragma unroll
            for (int r = 0; r < 4; r++) {
                const int row = tm * 16 + lq * 4 + r;
                ctx[(long)(b * NPOS + row) * DIM + h * HD + tn2 * 16 + lr] =
                    (__bf16)(O[tm][tn2][r] * inv[tm][r]);
            }
}

// ---------------------------------------------------------------------------
// FALLBACK (only if workspace too small): fused conv+attention, round-0 form.
// ---------------------------------------------------------------------------
#define Q0 0
#define K0 2560
#define P0 0
#define V0 5120

__global__ __launch_bounds__(64, 4)
void attn_fused(const __bf16* __restrict__ t, const float* __restrict__ dw_w,
                const float* __restrict__ dw_b, const float* __restrict__ mask,
                const float* __restrict__ rpb, __bf16* __restrict__ ctx)
{
    __shared__ __bf16 smem[7424];
    __shared__ float  rpb_h[225];
    const int bid = blockIdx.x;
    const int h   = bid >> 11;
    const int s_  = bid & 2047;
    const int b   = (s_ & 7) * 256 + (s_ >> 3);
    const int lane = threadIdx.x;
    const int lr = lane & 15, lq = lane >> 4;

    for (int i = lane; i < 225; i += 64) rpb_h[i] = rpb[i * HEADS + h];

    {
        const int kv = lane >> 5, d = lane & 31;
        const int o  = 192 + kv * 192 + h * 32 + d;
        float w[9];
#pragma unroll
        for (int tap = 0; tap < 9; tap++) w[tap] = dw_w[o * 9 + tap];
        const float cb = dw_b[o];
        const bool up = (b > 0), dn = (b < NWIN - 1);
        const __bf16* r1 = t + (long)b * NPOS * C3 + o;
        const __bf16* r0 = r1 - (long)NPOS * C3;
        const __bf16* r2 = r1 + (long)NPOS * C3;
        float p0 = 0.f, c0 = up ? (float)r0[0] : 0.f;
        float p1 = 0.f, c1 = (float)r1[0];
        float p2 = 0.f, c2 = dn ? (float)r2[0] : 0.f;
        const int base = kv ? (V0 + d * 72) : (K0 + d);
        const int step = kv ? 1 : 40;
        for (int nn = 0; nn < 64; nn++) {
            float n0 = 0.f, n1 = 0.f, n2 = 0.f;
            if (nn < 63) {
                const long off = (long)(nn + 1) * C3;
                if (up) n0 = (float)r0[off];
                n1 = (float)r1[off];
                if (dn) n2 = (float)r2[off];
            }
            float out = cb
                + w[0] * p0 + w[1] * c0 + w[2] * n0
                + w[3] * p1 + w[4] * c1 + w[5] * n1
                + w[6] * p2 + w[7] * c2 + w[8] * n2;
            smem[base + nn * step] = (__bf16)out;
            p0 = c0; c0 = n0; p1 = c1; c1 = n1; p2 = c2; c2 = n2;
        }
    }

    {
        float q[HD];
#pragma unroll
        for (int d = 0; d < HD; d++) q[d] = dw_b[h * HD + d];
#pragma unroll
        for (int kh = 0; kh < 3; kh++) {
            const int bb = b + kh - 1;
            if (bb < 0 || bb >= NWIN) continue;
#pragma unroll
            for (int kw = 0; kw < 3; kw++) {
                const int nn = lane + kw - 1;
                if (nn >= 0 && nn < NPOS) {
                    const b16x8* p = (const b16x8*)(t + (long)(bb * NPOS + nn) * C3 + h * HD);
#pragma unroll
                    for (int j = 0; j < 4; j++) {
                        b16x8 vv = p[j];
#pragma unroll
                        for (int e = 0; e < 8; e++)
                            q[j * 8 + e] += (float)vv[e] * dw_w[(h * HD + j * 8 + e) * 9 + kh * 3 + kw];
                    }
                }
            }
        }
#pragma unroll
        for (int d = 0; d < HD; d++) smem[Q0 + lane * 40 + d] = (__bf16)(q[d] * SCALE);
    }

    __syncthreads();

    b16x8 aq[4], bk[4];
#pragma unroll
    for (int tm = 0; tm < 4; tm++) aq[tm] = *(const b16x8*)&smem[Q0 + (tm * 16 + lr) * 40 + lq * 8];
#pragma unroll
    for (int tn = 0; tn < 4; tn++) bk[tn] = *(const b16x8*)&smem[K0 + (tn * 16 + lr) * 40 + lq * 8];
    f32x4 S[4][4];
#pragma unroll
    for (int tm = 0; tm < 4; tm++)
#pragma unroll
        for (int tn = 0; tn < 4; tn++) {
            S[tm][tn] = (f32x4){0.f, 0.f, 0.f, 0.f};
            S[tm][tn] = __builtin_amdgcn_mfma_f32_16x16x32_bf16(aq[tm], bk[tn], S[tm][tn], 0, 0, 0);
        }

    __syncthreads();

    const float* mbase = mask + (long)(b & 63) * 4096;
    float part[4][4];
#pragma unroll
    for (int tm = 0; tm < 4; tm++)
#pragma unroll
        for (int r = 0; r < 4; r++) part[tm][r] = 0.f;
#pragma unroll
    for (int tm = 0; tm < 4; tm++) {
#pragma unroll
        for (int r = 0; r < 4; r++) {
            const int row = tm * 16 + lq * 4 + r;
            const int rh = row >> 3, rw = row & 7;
#pragma unroll
            for (int tn = 0; tn < 4; tn++) {
                const int col = tn * 16 + lr;
                const int ridx = (rh - (col >> 3) + 7) * 15 + (rw - (col & 7) + 7);
                float sv = S[tm][tn][r] + rpb_h[ridx] + mbase[row * 64 + col];
                float ee = __expf(sv);
                part[tm][r] += ee;
                smem[P0 + row * 72 + col] = (__bf16)ee;
            }
        }
    }
#pragma unroll
    for (int st = 1; st < 16; st <<= 1)
#pragma unroll
        for (int tm = 0; tm < 4; tm++)
#pragma unroll
            for (int r = 0; r < 4; r++) part[tm][r] += __shfl_xor(part[tm][r], st);
    float inv[4][4];
#pragma unroll
    for (int tm = 0; tm < 4; tm++)
#pragma unroll
        for (int r = 0; r < 4; r++) inv[tm][r] = 1.0f / part[tm][r];

    __syncthreads();

    f32x4 O[4][2];
#pragma unroll
    for (int tm = 0; tm < 4; tm++)
#pragma unroll
        for (int tn2 = 0; tn2 < 2; tn2++) O[tm][tn2] = (f32x4){0.f, 0.f, 0.f, 0.f};
#pragma unroll
    for (int tk = 0; tk < 2; tk++) {
        b16x8 bv[2];
#pragma unroll
        for (int tn2 = 0; tn2 < 2; tn2++)
            bv[tn2] = *(const b16x8*)&smem[V0 + (tn2 * 16 + lr) * 72 + tk * 32 + lq * 8];
#pragma unroll
        for (int tm = 0; tm < 4; tm++) {
            b16x8 ap = *(const b16x8*)&smem[P0 + (tm * 16 + lr) * 72 + tk * 32 + lq * 8];
#pragma unroll
            for (int tn2 = 0; tn2 < 2; tn2++)
                O[tm][tn2] = __builtin_amdgcn_mfma_f32_16x16x32_bf16(ap, bv[tn2], O[tm][tn2], 0, 0, 0);
        }
    }

#pragma unroll
    for (int tm = 0; tm < 4; tm++)
#pragma unroll
        for (int tn2 = 0; tn2 < 2; tn2++)
#pragma unroll
            for (int r = 0; r < 4; r++) {
                const int row = tm * 16 + lq * 4 + r;
                ctx[(long)(b * NPOS + row) * DIM + h * HD + tn2 * 16 + lr] =
                    (__bf16)(O[tm][tn2][r] * inv[tm][r]);
            }
}

// ---------------------------------------------------------------------------
extern "C" void kernel_launch(void* const* d_in, const int* in_sizes, int n_in,
                              void* d_out, int out_size, void* d_ws, size_t ws_size,
                              hipStream_t stream)
{
    (void)in_sizes; (void)n_in; (void)out_size;
    const float* x      = (const float*)d_in[0];
    const float* mask   = (const float*)d_in[1];
    const float* qkv_w  = (const float*)d_in[2];
    const float* qkv_b  = (const float*)d_in[3];
    const float* dw_w   = (const float*)d_in[4];
    const float* dw_b   = (const float*)d_in[5];
    const float* rpb    = (const float*)d_in[6];
    const float* proj_w = (const float*)d_in[8];
    const float* proj_b = (const float*)d_in[9];
    float* out = (float*)d_out;

    __bf16* t = (__bf16*)d_ws;                         // (131072, 576) bf16 = 151 MB
    const size_t need = ((size_t)MTOT * C3 * 2 + (size_t)MTOT * DIM) * sizeof(__bf16);

    if (ws_size >= need) {
        __bf16* u   = t + (size_t)MTOT * C3;           // conv output, 151 MB
        __bf16* ctx = u + (size_t)MTOT * C3;           // 50 MB
        gemm_bt<float, float, __bf16, 192>
            <<<(MTOT / GTM) * (C3 / 192), 256, 0, stream>>>(x, qkv_w, qkv_b, t, C3);
        dwconv<<<NWIN * 3, 384, 0, stream>>>(t, dw_w, dw_b, u);
        attn_mfma<<<NWIN * HEADS, 64, 0, stream>>>(u, mask, rpb, ctx);
        gemm_bt<__bf16, float, float, 192>
            <<<(MTOT / GTM) * (DIM / 192), 256, 0, stream>>>(ctx, proj_w, proj_b, out, DIM);
    } else {
        __bf16* ctx = t + (size_t)MTOT * C3;
        gemm_bt<float, float, __bf16, 64>
            <<<(MTOT / GTM) * (C3 / 64), 256, 0, stream>>>(x, qkv_w, qkv_b, t, C3);
        attn_fused<<<NWIN * HEADS, 64, 0, stream>>>(t, dw_w, dw_b, mask, rpb, ctx);
        gemm_bt<__bf16, float, float, 64>
            <<<(MTOT / GTM) * (DIM / 64), 256, 0, stream>>>(ctx, proj_w, proj_b, out, DIM);
    }
}

// Round 8
// 488.084 us; speedup vs baseline: 1.0827x; 1.0827x over previous
//
#include <hip/hip_runtime.h>

#define NWIN 2048
#define NPOS 64
#define DIM  192
#define C3   576
#define HEADS 6
#define HD   32
#define MTOT (NWIN*NPOS)
#define SCALE 0.17677669529663687f

typedef __bf16 b16x8 __attribute__((ext_vector_type(8)));
typedef __bf16 b16x4 __attribute__((ext_vector_type(4)));
typedef float  f32x4 __attribute__((ext_vector_type(4)));

// load 8 contiguous elements as bf16x8, converting if fp32
__device__ __forceinline__ b16x8 ld8(const float* p) {
    const f32x4 f0 = *(const f32x4*)p;
    const f32x4 f1 = *(const f32x4*)(p + 4);
    b16x8 r;
    r[0] = (__bf16)f0[0]; r[1] = (__bf16)f0[1]; r[2] = (__bf16)f0[2]; r[3] = (__bf16)f0[3];
    r[4] = (__bf16)f1[0]; r[5] = (__bf16)f1[1]; r[6] = (__bf16)f1[2]; r[7] = (__bf16)f1[3];
    return r;
}
__device__ __forceinline__ b16x8 ld8(const __bf16* p) { return *(const b16x8*)p; }

// ---------------------------------------------------------------------------
// GEMM (B^T form): C[m][n] = sum_k A[m][k] * W[n][k] + bias[n]
// Tile 128(M) x GTNT(N), BK=64 (3 chunks), 256 threads = 4 waves.
// GTNT=192: A panel re-read N/192 times (3x for C3, 1x for DIM) instead of 9x.
// LDS = (128+192)*72*2 = 45 KB; 3 blocks/CU = 135 KB <= 160 KB.
// XCD-chunk swizzle: every grid used here is a multiple of 8.
// ---------------------------------------------------------------------------
#define GTM 128
#define GLD 72

template <typename TA, typename TW, typename TC, int GTNT>
__global__ __launch_bounds__(256, 3)
void gemm_bt(const TA* __restrict__ A, const TW* __restrict__ W,
             const float* __restrict__ bias, TC* __restrict__ C, int N)
{
    constexpr int NT = GTNT / 16;
    __shared__ __bf16 As[GTM][GLD];
    __shared__ __bf16 Ws[GTNT][GLD];
    const int ntiles = N / GTNT;
    const int cpx = gridDim.x >> 3;                       // grid % 8 == 0
    const int lb  = (blockIdx.x & 7) * cpx + (blockIdx.x >> 3);
    const int bm = lb / ntiles;
    const int bn = lb % ntiles;
    const long m0 = (long)bm * GTM;
    const int  n0 = bn * GTNT;
    const int tid  = threadIdx.x;
    const int wave = tid >> 6, lane = tid & 63;
    const int lr = lane & 15, lq = lane >> 4;

    f32x4 acc[2][NT];
#pragma unroll
    for (int i = 0; i < 2; i++)
#pragma unroll
        for (int j = 0; j < NT; j++) acc[i][j] = (f32x4){0.f, 0.f, 0.f, 0.f};

    for (int kc = 0; kc < 3; kc++) {
#pragma unroll
        for (int i = 0; i < 4; i++) {
            int idx = tid + i * 256;
            int r = idx >> 3, c = idx & 7;
            *(b16x8*)&As[r][c * 8] = ld8(A + (m0 + r) * 192 + kc * 64 + c * 8);
        }
#pragma unroll
        for (int i = 0; i < GTNT / 32; i++) {
            int idx = tid + i * 256;
            int r = idx >> 3, c = idx & 7;
            *(b16x8*)&Ws[r][c * 8] = ld8(W + (long)(n0 + r) * 192 + kc * 64 + c * 8);
        }
        __syncthreads();
#pragma unroll
        for (int kt = 0; kt < 2; kt++) {
            const int k0 = kt * 32 + lq * 8;
            b16x8 a0 = *(const b16x8*)&As[wave * 32 + lr][k0];
            b16x8 a1 = *(const b16x8*)&As[wave * 32 + 16 + lr][k0];
#pragma unroll
            for (int tn = 0; tn < NT; tn++) {
                b16x8 bb = *(const b16x8*)&Ws[tn * 16 + lr][k0];
                acc[0][tn] = __builtin_amdgcn_mfma_f32_16x16x32_bf16(a0, bb, acc[0][tn], 0, 0, 0);
                acc[1][tn] = __builtin_amdgcn_mfma_f32_16x16x32_bf16(a1, bb, acc[1][tn], 0, 0, 0);
            }
        }
        __syncthreads();
    }
#pragma unroll
    for (int tn = 0; tn < NT; tn++) {
        float bv = bias[n0 + tn * 16 + lr];
#pragma unroll
        for (int tm = 0; tm < 2; tm++) {
#pragma unroll
            for (int r = 0; r < 4; r++) {
                long row = m0 + wave * 32 + tm * 16 + lq * 4 + r;
                C[row * N + (n0 + tn * 16 + lr)] = (TC)(acc[tm][tn][r] + bv);
            }
        }
    }
}

// ---------------------------------------------------------------------------
// Depthwise 3x3 conv, v4: bulk LDS staging.
// Block = (window b, channel-third gq, col-half hf). 192 threads = 3 waves.
// grid = 2048*3*2 = 12288, XCD-chunk swizzled (6 blocks of a window adjacent).
// Phase 1: stage 3 rows x 34 cols x 192 ch (39,168 B) into LDS with 13
//   independent coalesced b16x8 loads/thread (halos zero-filled in LDS).
// Phase 2: v2's rolling-window compute, guard-free, 3x ds_read_b64/iter.
//   Identical FMA order to v2 -> bitwise-identical results.
// 4 blocks/CU (156 KB LDS), latency hidden by the deep staging pipeline.
// ---------------------------------------------------------------------------
__device__ __forceinline__ void ld4f(float* d, const __bf16* p) {
    b16x4 v = *(const b16x4*)p;
    d[0] = (float)v[0]; d[1] = (float)v[1]; d[2] = (float)v[2]; d[3] = (float)v[3];
}

__global__ __launch_bounds__(192)
void dwconv(const __bf16* __restrict__ t, const float* __restrict__ dw_w,
            const float* __restrict__ dw_b, __bf16* __restrict__ u)
{
    __shared__ __bf16 sbuf[3 * 34 * 192];               // 39,168 B
    const int tid = threadIdx.x;
    const int cg  = tid % 48;
    const int mr  = tid / 48;                           // 0..3
    const int cpx = gridDim.x >> 3;
    const int lb  = (blockIdx.x & 7) * cpx + (blockIdx.x >> 3);
    const int b   = lb / 6;
    const int rem = lb % 6;
    const int gq  = rem >> 1;                           // channel-third
    const int hf  = rem & 1;                            // col-half

    // ---- Phase 1: stage input slab (2448 x 16B chunks) ----
#pragma unroll
    for (int k = 0; k < 13; k++) {
        const int c = tid + k * 192;
        if (c < 2448) {
            const int p = c / 24, off16 = c % 24;       // 24 chunks per (row,col) piece
            const int r = p / 34, nn = p % 34;
            const int row  = b - 1 + r;
            const int gcol = hf * 32 + nn - 1;
            b16x8 v = {};
            if ((unsigned)row < NWIN && (unsigned)gcol < NPOS)
                v = *(const b16x8*)(t + ((long)row * NPOS + gcol) * C3 + gq * 192 + off16 * 8);
            *(b16x8*)&sbuf[c * 8] = v;
        }
    }

    // weights/bias while staging is in flight
    const float sc = (gq == 0) ? SCALE : 1.0f;
    const int ch0 = gq * 192 + cg * 4;
    float w[9][4], bs[4];
#pragma unroll
    for (int e = 0; e < 4; e++) {
        bs[e] = dw_b[ch0 + e] * sc;
#pragma unroll
        for (int tp = 0; tp < 9; tp++) w[tp][e] = dw_w[(ch0 + e) * 9 + tp] * sc;
    }

    __syncthreads();

    // ---- Phase 2: rolling-window compute from LDS (guard-free) ----
    const int base = cg * 4;
    float p0[4], p1[4], p2[4], c0[4], c1[4], c2[4];
    {
        const int nn = mr * 8;                          // local col of (first output - 1)
        ld4f(p0, &sbuf[(0 * 34 + nn) * 192 + base]);
        ld4f(p1, &sbuf[(1 * 34 + nn) * 192 + base]);
        ld4f(p2, &sbuf[(2 * 34 + nn) * 192 + base]);
        ld4f(c0, &sbuf[(0 * 34 + nn + 1) * 192 + base]);
        ld4f(c1, &sbuf[(1 * 34 + nn + 1) * 192 + base]);
        ld4f(c2, &sbuf[(2 * 34 + nn + 1) * 192 + base]);
    }
    const int gn0 = hf * 32 + mr * 8;
    __bf16* ub = u + ((long)b * NPOS + gn0) * C3 + ch0;

#pragma unroll
    for (int j = 0; j < 8; j++) {
        const int nn = mr * 8 + j + 2;                  // local col of (output + 1)
        float x0[4], x1[4], x2[4];
        ld4f(x0, &sbuf[(0 * 34 + nn) * 192 + base]);
        ld4f(x1, &sbuf[(1 * 34 + nn) * 192 + base]);
        ld4f(x2, &sbuf[(2 * 34 + nn) * 192 + base]);
        b16x4 o;
#pragma unroll
        for (int e = 0; e < 4; e++) {
            float a = bs[e]
                + w[0][e] * p0[e] + w[1][e] * c0[e] + w[2][e] * x0[e]
                + w[3][e] * p1[e] + w[4][e] * c1[e] + w[5][e] * x1[e]
                + w[6][e] * p2[e] + w[7][e] * c2[e] + w[8][e] * x2[e];
            o[e] = (__bf16)a;
        }
        *(b16x4*)(ub + (long)j * C3) = o;
#pragma unroll
        for (int e = 0; e < 4; e++) {
            p0[e] = c0[e]; c0[e] = x0[e];
            p1[e] = c1[e]; c1[e] = x1[e];
            p2[e] = c2[e]; c2[e] = x2[e];
        }
    }
}

// ---------------------------------------------------------------------------
// MFMA window attention on pre-conv'd qkv (u). One wave per (b, h). Unchanged.
// ---------------------------------------------------------------------------
#define P0v2 0
#define VT0  4608

__global__ __launch_bounds__(64, 3)
void attn_mfma(const __bf16* __restrict__ u, const float* __restrict__ mask,
               const float* __restrict__ rpb, __bf16* __restrict__ ctx)
{
    __shared__ __bf16 smem[4608 + 2304];
    __shared__ float  rpb_h[225];
    const int cpx = gridDim.x >> 3;
    const int lb  = (blockIdx.x & 7) * cpx + (blockIdx.x >> 3);
    const int b = lb / HEADS;
    const int h = lb % HEADS;
    const int lane = threadIdx.x;
    const int lr = lane & 15, lq = lane >> 4;

    for (int i = lane; i < 225; i += 64) rpb_h[i] = rpb[i * HEADS + h];

    const __bf16* ub = u + (long)b * NPOS * C3 + h * HD;

    {
        const __bf16* vp = ub + (long)lane * C3 + 2 * DIM;
        b16x8 v0 = *(const b16x8*)vp;
        b16x8 v1 = *(const b16x8*)(vp + 8);
        b16x8 v2 = *(const b16x8*)(vp + 16);
        b16x8 v3 = *(const b16x8*)(vp + 24);
#pragma unroll
        for (int e = 0; e < 8; e++) {
            smem[VT0 + (e     ) * 72 + lane] = v0[e];
            smem[VT0 + (e +  8) * 72 + lane] = v1[e];
            smem[VT0 + (e + 16) * 72 + lane] = v2[e];
            smem[VT0 + (e + 24) * 72 + lane] = v3[e];
        }
    }

    b16x8 aq[4], bk[4];
#pragma unroll
    for (int t4 = 0; t4 < 4; t4++) {
        aq[t4] = *(const b16x8*)(ub + (long)(t4 * 16 + lr) * C3 +       lq * 8);
        bk[t4] = *(const b16x8*)(ub + (long)(t4 * 16 + lr) * C3 + DIM + lq * 8);
    }

    f32x4 S[4][4];
#pragma unroll
    for (int tm = 0; tm < 4; tm++)
#pragma unroll
        for (int tn = 0; tn < 4; tn++) {
            S[tm][tn] = (f32x4){0.f, 0.f, 0.f, 0.f};
            S[tm][tn] = __builtin_amdgcn_mfma_f32_16x16x32_bf16(aq[tm], bk[tn], S[tm][tn], 0, 0, 0);
        }

    __syncthreads();

    const float* mbase = mask + (long)(b & 63) * 4096;
    float part[4][4];
#pragma unroll
    for (int tm = 0; tm < 4; tm++)
#pragma unroll
        for (int r = 0; r < 4; r++) part[tm][r] = 0.f;
#pragma unroll
    for (int tm = 0; tm < 4; tm++) {
#pragma unroll
        for (int r = 0; r < 4; r++) {
            const int row = tm * 16 + lq * 4 + r;
            const int rh = row >> 3, rw = row & 7;
#pragma unroll
            for (int tn = 0; tn < 4; tn++) {
                const int col = tn * 16 + lr;
                const int ridx = (rh - (col >> 3) + 7) * 15 + (rw - (col & 7) + 7);
                float sv = S[tm][tn][r] + rpb_h[ridx] + mbase[row * 64 + col];
                float ee = __expf(sv);
                part[tm][r] += ee;
                smem[P0v2 + row * 72 + col] = (__bf16)ee;
            }
        }
    }
#pragma unroll
    for (int st = 1; st < 16; st <<= 1)
#pragma unroll
        for (int tm = 0; tm < 4; tm++)
#pragma unroll
            for (int r = 0; r < 4; r++) part[tm][r] += __shfl_xor(part[tm][r], st);
    float inv[4][4];
#pragma unroll
    for (int tm = 0; tm < 4; tm++)
#pragma unroll
        for (int r = 0; r < 4; r++) inv[tm][r] = 1.0f / part[tm][r];

    __syncthreads();

    f32x4 O[4][2];
#pragma unroll
    for (int tm = 0; tm < 4; tm++)
#pragma unroll
        for (int tn2 = 0; tn2 < 2; tn2++) O[tm][tn2] = (f32x4){0.f, 0.f, 0.f, 0.f};
#pragma unroll
    for (int tk = 0; tk < 2; tk++) {
        b16x8 bv[2];
#pragma unroll
        for (int tn2 = 0; tn2 < 2; tn2++)
            bv[tn2] = *(const b16x8*)&smem[VT0 + (tn2 * 16 + lr) * 72 + tk * 32 + lq * 8];
#pragma unroll
        for (int tm = 0; tm < 4; tm++) {
            b16x8 ap = *(const b16x8*)&smem[P0v2 + (tm * 16 + lr) * 72 + tk * 32 + lq * 8];
#pragma unroll
            for (int tn2 = 0; tn2 < 2; tn2++)
                O[tm][tn2] = __builtin_amdgcn_mfma_f32_16x16x32_bf16(ap, bv[tn2], O[tm][tn2], 0, 0, 0);
        }
    }

#pragma unroll
    for (int tm = 0; tm < 4; tm++)
#pragma unroll
        for (int tn2 = 0; tn2 < 2; tn2++)
#pragma unroll
            for (int r = 0; r < 4; r++) {
                const int row = tm * 16 + lq * 4 + r;
                ctx[(long)(b * NPOS + row) * DIM + h * HD + tn2 * 16 + lr] =
                    (__bf16)(O[tm][tn2][r] * inv[tm][r]);
            }
}

// ---------------------------------------------------------------------------
// FALLBACK (only if workspace too small): fused conv+attention, round-0 form.
// ---------------------------------------------------------------------------
#define Q0 0
#define K0 2560
#define P0 0
#define V0 5120

__global__ __launch_bounds__(64, 4)
void attn_fused(const __bf16* __restrict__ t, const float* __restrict__ dw_w,
                const float* __restrict__ dw_b, const float* __restrict__ mask,
                const float* __restrict__ rpb, __bf16* __restrict__ ctx)
{
    __shared__ __bf16 smem[7424];
    __shared__ float  rpb_h[225];
    const int bid = blockIdx.x;
    const int h   = bid >> 11;
    const int s_  = bid & 2047;
    const int b   = (s_ & 7) * 256 + (s_ >> 3);
    const int lane = threadIdx.x;
    const int lr = lane & 15, lq = lane >> 4;

    for (int i = lane; i < 225; i += 64) rpb_h[i] = rpb[i * HEADS + h];

    {
        const int kv = lane >> 5, d = lane & 31;
        const int o  = 192 + kv * 192 + h * 32 + d;
        float w[9];
#pragma unroll
        for (int tap = 0; tap < 9; tap++) w[tap] = dw_w[o * 9 + tap];
        const float cb = dw_b[o];
        const bool up = (b > 0), dn = (b < NWIN - 1);
        const __bf16* r1 = t + (long)b * NPOS * C3 + o;
        const __bf16* r0 = r1 - (long)NPOS * C3;
        const __bf16* r2 = r1 + (long)NPOS * C3;
        float p0 = 0.f, c0 = up ? (float)r0[0] : 0.f;
        float p1 = 0.f, c1 = (float)r1[0];
        float p2 = 0.f, c2 = dn ? (float)r2[0] : 0.f;
        const int base = kv ? (V0 + d * 72) : (K0 + d);
        const int step = kv ? 1 : 40;
        for (int nn = 0; nn < 64; nn++) {
            float n0 = 0.f, n1 = 0.f, n2 = 0.f;
            if (nn < 63) {
                const long off = (long)(nn + 1) * C3;
                if (up) n0 = (float)r0[off];
                n1 = (float)r1[off];
                if (dn) n2 = (float)r2[off];
            }
            float out = cb
                + w[0] * p0 + w[1] * c0 + w[2] * n0
                + w[3] * p1 + w[4] * c1 + w[5] * n1
                + w[6] * p2 + w[7] * c2 + w[8] * n2;
            smem[base + nn * step] = (__bf16)out;
            p0 = c0; c0 = n0; p1 = c1; c1 = n1; p2 = c2; c2 = n2;
        }
    }

    {
        float q[HD];
#pragma unroll
        for (int d = 0; d < HD; d++) q[d] = dw_b[h * HD + d];
#pragma unroll
        for (int kh = 0; kh < 3; kh++) {
            const int bb = b + kh - 1;
            if (bb < 0 || bb >= NWIN) continue;
#pragma unroll
            for (int kw = 0; kw < 3; kw++) {
                const int nn = lane + kw - 1;
                if (nn >= 0 && nn < NPOS) {
                    const b16x8* p = (const b16x8*)(t + (long)(bb * NPOS + nn) * C3 + h * HD);
#pragma unroll
                    for (int j = 0; j < 4; j++) {
                        b16x8 vv = p[j];
#pragma unroll
                        for (int e = 0; e < 8; e++)
                            q[j * 8 + e] += (float)vv[e] * dw_w[(h * HD + j * 8 + e) * 9 + kh * 3 + kw];
                    }
                }
            }
        }
#pragma unroll
        for (int d = 0; d < HD; d++) smem[Q0 + lane * 40 + d] = (__bf16)(q[d] * SCALE);
    }

    __syncthreads();

    b16x8 aq[4], bk[4];
#pragma unroll
    for (int tm = 0; tm < 4; tm++) aq[tm] = *(const b16x8*)&smem[Q0 + (tm * 16 + lr) * 40 + lq * 8];
#pragma unroll
    for (int tn = 0; tn < 4; tn++) bk[tn] = *(const b16x8*)&smem[K0 + (tn * 16 + lr) * 40 + lq * 8];
    f32x4 S[4][4];
#pragma unroll
    for (int tm = 0; tm < 4; tm++)
#pragma unroll
        for (int tn = 0; tn < 4; tn++) {
            S[tm][tn] = (f32x4){0.f, 0.f, 0.f, 0.f};
            S[tm][tn] = __builtin_amdgcn_mfma_f32_16x16x32_bf16(aq[tm], bk[tn], S[tm][tn], 0, 0, 0);
        }

    __syncthreads();

    const float* mbase = mask + (long)(b & 63) * 4096;
    float part[4][4];
#pragma unroll
    for (int tm = 0; tm < 4; tm++)
#pragma unroll
        for (int r = 0; r < 4; r++) part[tm][r] = 0.f;
#pragma unroll
    for (int tm = 0; tm < 4; tm++) {
#pragma unroll
        for (int r = 0; r < 4; r++) {
            const int row = tm * 16 + lq * 4 + r;
            const int rh = row >> 3, rw = row & 7;
#pragma unroll
            for (int tn = 0; tn < 4; tn++) {
                const int col = tn * 16 + lr;
                const int ridx = (rh - (col >> 3) + 7) * 15 + (rw - (col & 7) + 7);
                float sv = S[tm][tn][r] + rpb_h[ridx] + mbase[row * 64 + col];
                float ee = __expf(sv);
                part[tm][r] += ee;
                smem[P0 + row * 72 + col] = (__bf16)ee;
            }
        }
    }
#pragma unroll
    for (int st = 1; st < 16; st <<= 1)
#pragma unroll
        for (int tm = 0; tm < 4; tm++)
#pragma unroll
            for (int r = 0; r < 4; r++) part[tm][r] += __shfl_xor(part[tm][r], st);
    float inv[4][4];
#pragma unroll
    for (int tm = 0; tm < 4; tm++)
#pragma unroll
        for (int r = 0; r < 4; r++) inv[tm][r] = 1.0f / part[tm][r];

    __syncthreads();

    f32x4 O[4][2];
#pragma unroll
    for (int tm = 0; tm < 4; tm++)
#pragma unroll
        for (int tn2 = 0; tn2 < 2; tn2++) O[tm][tn2] = (f32x4){0.f, 0.f, 0.f, 0.f};
#pragma unroll
    for (int tk = 0; tk < 2; tk++) {
        b16x8 bv[2];
#pragma unroll
        for (int tn2 = 0; tn2 < 2; tn2++)
            bv[tn2] = *(const b16x8*)&smem[V0 + (tn2 * 16 + lr) * 72 + tk * 32 + lq * 8];
#pragma unroll
        for (int tm = 0; tm < 4; tm++) {
            b16x8 ap = *(const b16x8*)&smem[P0 + (tm * 16 + lr) * 72 + tk * 32 + lq * 8];
#pragma unroll
            for (int tn2 = 0; tn2 < 2; tn2++)
                O[tm][tn2] = __builtin_amdgcn_mfma_f32_16x16x32_bf16(ap, bv[tn2], O[tm][tn2], 0, 0, 0);
        }
    }

#pragma unroll
    for (int tm = 0; tm < 4; tm++)
#pragma unroll
        for (int tn2 = 0; tn2 < 2; tn2++)
#pragma unroll
            for (int r = 0; r < 4; r++) {
                const int row = tm * 16 + lq * 4 + r;
                ctx[(long)(b * NPOS + row) * DIM + h * HD + tn2 * 16 + lr] =
                    (__bf16)(O[tm][tn2][r] * inv[tm][r]);
            }
}

// ---------------------------------------------------------------------------
extern "C" void kernel_launch(void* const* d_in, const int* in_sizes, int n_in,
                              void* d_out, int out_size, void* d_ws, size_t ws_size,
                              hipStream_t stream)
{
    (void)in_sizes; (void)n_in; (void)out_size;
    const float* x      = (const float*)d_in[0];
    const float* mask   = (const float*)d_in[1];
    const float* qkv_w  = (const float*)d_in[2];
    const float* qkv_b  = (const float*)d_in[3];
    const float* dw_w   = (const float*)d_in[4];
    const float* dw_b   = (const float*)d_in[5];
    const float* rpb    = (const float*)d_in[6];
    const float* proj_w = (const float*)d_in[8];
    const float* proj_b = (const float*)d_in[9];
    float* out = (float*)d_out;

    __bf16* t = (__bf16*)d_ws;                         // (131072, 576) bf16 = 151 MB
    const size_t need = ((size_t)MTOT * C3 * 2 + (size_t)MTOT * DIM) * sizeof(__bf16);

    if (ws_size >= need) {
        __bf16* u   = t + (size_t)MTOT * C3;           // conv output, 151 MB
        __bf16* ctx = u + (size_t)MTOT * C3;           // 50 MB
        gemm_bt<float, float, __bf16, 192>
            <<<(MTOT / GTM) * (C3 / 192), 256, 0, stream>>>(x, qkv_w, qkv_b, t, C3);
        dwconv<<<NWIN * 6, 192, 0, stream>>>(t, dw_w, dw_b, u);
        attn_mfma<<<NWIN * HEADS, 64, 0, stream>>>(u, mask, rpb, ctx);
        gemm_bt<__bf16, float, float, 192>
            <<<(MTOT / GTM) * (DIM / 192), 256, 0, stream>>>(ctx, proj_w, proj_b, out, DIM);
    } else {
        __bf16* ctx = t + (size_t)MTOT * C3;
        gemm_bt<float, float, __bf16, 64>
            <<<(MTOT / GTM) * (C3 / 64), 256, 0, stream>>>(x, qkv_w, qkv_b, t, C3);
        attn_fused<<<NWIN * HEADS, 64, 0, stream>>>(t, dw_w, dw_b, mask, rpb, ctx);
        gemm_bt<__bf16, float, float, 64>
            <<<(MTOT / GTM) * (DIM / 64), 256, 0, stream>>>(ctx, proj_w, proj_b, out, DIM);
    }
}